// Round 1
// baseline (174.797 us; speedup 1.0000x reference)
//
#include <hip/hip_runtime.h>
#include <math.h>

#define TT 750
#define HH 64
#define BB 8
#define UP 96
#define NS (TT*UP)          // 72000 samples
#define NCHAIN (BB*HH)      // 512
#define NYQ 12000.0
#define LN10 2.302585092994045684
#define TWO_PI 6.283185307179586476925286766559
#define INV_TWO_PI 0.15915494309189533576888376337251
#define KPH (TWO_PI / 24000.0)

// ---------------- Kernel A: per-frame controls ----------------
// One wave (64 lanes) per (b,t) frame; lane = harmonic index.
__global__ void k_controls(const float* __restrict__ amp_in,
                           const float* __restrict__ hd_in,
                           const float* __restrict__ inh_in,
                           const float* __restrict__ f0_in,
                           double* __restrict__ Fd,
                           float* __restrict__ Ha) {
    int wid  = threadIdx.x >> 6;
    int lane = threadIdx.x & 63;
    int frame = blockIdx.x * 4 + wid;
    if (frame >= BB * TT) return;
    int b = frame / TT;
    int t = frame - b * TT;

    double f0   = (double)f0_in[frame];
    double araw = (double)amp_in[frame];
    double bc   = (double)inh_in[frame];
    bc = bc > 0.0 ? bc : 0.0;

    // scale_function: 2*sigmoid(x)^ln(10) + 1e-7   (f64 to track np ref)
    double amp = 2.0 * pow(1.0 / (1.0 + exp(-araw)), LN10) + 1e-7;
    if (!(f0 > 20.0)) amp = 0.0;

    double hraw = (double)hd_in[frame * HH + lane];
    double hd   = 2.0 * pow(1.0 / (1.0 + exp(-hraw)), LN10) + 1e-7;

    double k = (double)(lane + 1);
    double stretch = sqrt(1.0 + bc * k * k);
    double inh = (f0 * k) * stretch;                 // inharmonic frequency
    double den = fmax(f0, 1e-4) * k;
    double shift = inh / (den == 0.0 ? 1e-7 : den) - 1.0;

    if (!(inh < NYQ)) hd = 0.0;                      // remove_above_nyquist

    // wave-wide sum over the 64 harmonics (normalization denominator)
    double ssum = hd;
    for (int off = 32; off; off >>= 1) ssum += __shfl_xor(ssum, off);
    double hdn = hd / (ssum == 0.0 ? 1e-7 : ssum);   // safe_divide

    double hf = (f0 * k) * (1.0 + shift);            // harmonic_frequencies

    int chain = b * HH + lane;
    Fd[chain * TT + t] = hf;
    Ha[chain * TT + t] = (float)(amp * hdn);
}

// ---------------- Kernel B: interpolation-weight prefix tables ----------------
// Reproduces the reference's f32-rounded weights w(s) = f32(s/96) - i0 and
// accumulates per-frame inclusive prefixes in f64.
__global__ void k_wtab(double* __restrict__ Vt, double* __restrict__ Wt) {
    int i = blockIdx.x * blockDim.x + threadIdx.x;
    if (i >= TT) return;
    double acc = 0.0;
    for (int j = 0; j < UP; ++j) {
        int s = i * UP + j;
        float t = (float)s / 96.0f;      // exactly the reference's t
        float w = t - (float)i;          // exact f32 subtract (Sterbenz)
        acc += (double)w;
        Vt[i * UP + j] = acc;
    }
    Wt[i] = acc;
}

// ---------------- Kernel C: frame-boundary phase prefix per chain ----------------
// One wave per (b,h) chain; 12 scan iterations over 750 frames.
__global__ void k_phase(const double* __restrict__ Fd,
                        const double* __restrict__ Wt,
                        double* __restrict__ Pd) {
    int lane  = threadIdx.x & 63;
    int chain = blockIdx.x * 4 + (threadIdx.x >> 6);
    if (chain >= NCHAIN) return;
    const double* F = Fd + chain * TT;
    double* P = Pd + chain * TT;
    double carry = 0.0;
    for (int g = 0; g < (TT + 63) / 64; ++g) {
        int i = g * 64 + lane;
        double own = 0.0;
        if (i < TT) {
            double flo = F[i];
            double fhi = F[min(i + 1, TT - 1)];
            own = KPH * (96.0 * flo + Wt[i] * (fhi - flo)); // sum of 96 increments
        }
        double incl = own;
        for (int off = 1; off < 64; off <<= 1) {
            double o = __shfl_up(incl, off);
            if (lane >= off) incl += o;
        }
        if (i < TT) P[i] = carry + (incl - own);  // exclusive prefix = frame-start phase
        carry += __shfl(incl, 63);
    }
}

// ---------------- Kernel D: synthesis ----------------
// One thread per (b, s); loops 64 harmonics in registers; no atomics.
__global__ void k_synth(const double* __restrict__ Fd,
                        const double* __restrict__ Pd,
                        const float*  __restrict__ Ha,
                        const double* __restrict__ Vt,
                        float* __restrict__ out) {
    int g = blockIdx.x * blockDim.x + threadIdx.x;
    if (g >= BB * NS) return;
    int b = g / NS;
    int s = g - b * NS;
    int i0 = s / UP;
    int j  = s - i0 * UP;
    int i1 = min(i0 + 1, TT - 1);
    float w32 = (float)s / 96.0f - (float)i0;
    double w64 = (double)w32;
    double V   = Vt[i0 * UP + j];
    double jp1 = (double)(j + 1);

    float acc = 0.0f;
    int base0 = b * HH * TT;
    for (int h = 0; h < HH; ++h) {
        int base = base0 + h * TT;
        double flo = Fd[base + i0];
        double fhi = Fd[base + i1];
        double dlt = fhi - flo;
        double phase = Pd[base + i0] + KPH * (jp1 * flo + V * dlt);
        double y  = phase * INV_TWO_PI;
        double fr = y - rint(y);                      // phase mod 2pi, in revolutions
        float  c  = cosf((float)fr * (float)TWO_PI);  // |arg| <= pi: fast accurate path
        double freq = flo + w64 * dlt;                // sample-level frequency envelope
        float alo = Ha[base + i0], ahi = Ha[base + i1];
        float a = alo * (1.0f - w32) + ahi * w32;
        if (freq < NYQ) acc += c * a;                 // remove_above_nyquist at sample level
    }
    out[g] = acc;
}

extern "C" void kernel_launch(void* const* d_in, const int* in_sizes, int n_in,
                              void* d_out, int out_size, void* d_ws, size_t ws_size,
                              hipStream_t stream) {
    const float* amp_in = (const float*)d_in[0];   // (8,750,1)
    const float* hd_in  = (const float*)d_in[1];   // (8,750,64)
    const float* inh_in = (const float*)d_in[2];   // (8,750,1)
    const float* f0_in  = (const float*)d_in[3];   // (8,750,1)
    float* out = (float*)d_out;                    // (8,72000)

    char* ws = (char*)d_ws;
    double* Fd = (double*)(ws);                           // 512*750 doubles = 3,072,000 B
    double* Pd = (double*)(ws + 3072000);                 // 3,072,000 B
    float*  Ha = (float*)(ws + 6144000);                  // 1,536,000 B
    double* Vt = (double*)(ws + 7680000);                 // 72000 doubles = 576,000 B
    double* Wt = (double*)(ws + 8256000);                 // 750 doubles = 6,000 B

    // A: 6000 frames, 4 per block (1 wave each)
    k_controls<<<(BB * TT) / 4, 256, 0, stream>>>(amp_in, hd_in, inh_in, f0_in, Fd, Ha);
    // B: weight tables
    k_wtab<<<3, 256, 0, stream>>>(Vt, Wt);
    // C: 512 chains, 4 per block
    k_phase<<<NCHAIN / 4, 256, 0, stream>>>(Fd, Wt, Pd);
    // D: one thread per output sample
    k_synth<<<(BB * NS) / 256, 256, 0, stream>>>(Fd, Pd, Ha, Vt, out);
}

// Round 3
// 112.315 us; speedup vs baseline: 1.5563x; 1.5563x over previous
//
#include <hip/hip_runtime.h>
#include <math.h>

#define TT 750
#define HH 64
#define BB 8
#define UP 96
#define NS (TT*UP)          // 72000 samples per batch
#define NCHAIN (BB*HH)      // 512
#define NYQ 12000.0
#define LN10 2.302585092994045684

// ws layout:
//   TabP : float4[6000*64]  {p0rev, frev, drev, a0}   6,144,000 B @ 0
//   OwnR : double[6000*64]  per-(frame,h) frame phase increment (revolutions)
//                                                     3,072,000 B @ 6,144,000
//   Cut  : int8[6000*64]    nyquist cut index           384,000 B @ 9,216,000
#define OFF_OWNR 6144000
#define OFF_CUT  9216000

__device__ inline float fract_f32(float x) {
#if __has_builtin(__builtin_amdgcn_fractf)
    return __builtin_amdgcn_fractf(x);
#else
    return x - floorf(x);
#endif
}

__device__ inline float cos_rev(float fr) {   // cos(2*pi*fr), fr in [0,1)
#if __has_builtin(__builtin_amdgcn_cosf)
    return __builtin_amdgcn_cosf(fr);
#else
    return __cosf(fr * 6.28318530717958647692f);
#endif
}

// ---------------- Kernel A: per-frame controls (f64) ----------------
// One wave per (b,t) frame; lane = harmonic h. Computes this frame's and the
// next frame's harmonic frequency (freq needs no pow), the normalized
// amplitude, the per-frame phase increment (exact weights: sum_j j/96 = 47.5),
// and the exact f64 Nyquist cut index for the sample-level mask.
__global__ void k_controls(const float* __restrict__ amp_in,
                           const float* __restrict__ hd_in,
                           const float* __restrict__ inh_in,
                           const float* __restrict__ f0_in,
                           float4* __restrict__ TabP,
                           double* __restrict__ OwnR,
                           signed char* __restrict__ Cut) {
    int wid  = threadIdx.x >> 6;
    int lane = threadIdx.x & 63;
    int frame = blockIdx.x * 4 + wid;
    if (frame >= BB * TT) return;
    int b = frame / TT;
    int t = frame - b * TT;
    int tn = min(t + 1, TT - 1);
    int frame_n = b * TT + tn;

    double k = (double)(lane + 1);

    // --- this frame ---
    double f0 = (double)f0_in[frame];
    double bc = (double)inh_in[frame];   bc = bc > 0.0 ? bc : 0.0;
    double stretch = sqrt(1.0 + bc * k * k);
    double inh = (f0 * k) * stretch;
    double den = fmax(f0, 1e-4) * k;
    double shift = inh / (den == 0.0 ? 1e-7 : den) - 1.0;
    double flo = (f0 * k) * (1.0 + shift);          // harmonic_frequencies

    // --- next frame's frequency (same math, no pow needed) ---
    double f0n = (double)f0_in[frame_n];
    double bcn = (double)inh_in[frame_n]; bcn = bcn > 0.0 ? bcn : 0.0;
    double strn = sqrt(1.0 + bcn * k * k);
    double inhn = (f0n * k) * strn;
    double denn = fmax(f0n, 1e-4) * k;
    double shfn = inhn / (denn == 0.0 ? 1e-7 : denn) - 1.0;
    double fhi = (f0n * k) * (1.0 + shfn);

    // --- amplitudes ---
    double araw = (double)amp_in[frame];
    double amp = 2.0 * pow(1.0 / (1.0 + exp(-araw)), LN10) + 1e-7;
    if (!(f0 > 20.0)) amp = 0.0;
    double hraw = (double)hd_in[frame * HH + lane];
    double hd   = 2.0 * pow(1.0 / (1.0 + exp(-hraw)), LN10) + 1e-7;
    if (!(inh < NYQ)) hd = 0.0;                     // frame-level nyquist cut
    double ssum = hd;
    for (int off = 32; off; off >>= 1) ssum += __shfl_xor(ssum, off);
    double a = amp * (hd / (ssum == 0.0 ? 1e-7 : ssum));

    double dlt = fhi - flo;

    // --- exact Nyquist cut index (monotone mask in j) ---
    // mask_np(j) = flo*(1-w) + fhi*w < 12000, w = (t*96+j)/96 - t  (f64)
    int c8;
    {
        auto maskj = [&](int j) -> bool {
            double w = (double)(t * UP + j) / 96.0 - (double)t;
            double fr = flo * (1.0 - w) + fhi * w;
            return fr < NYQ;
        };
        if (dlt >= 0.0) {
            int jc;
            if (dlt == 0.0) jc = maskj(0) ? 96 : 0;
            else {
                double wst = (NYQ - flo) / dlt;
                double jr = wst * 96.0;
                jc = (jr < 0.0) ? 0 : (jr > 96.0 ? 96 : (int)floor(jr));
                while (jc < 96 && maskj(jc)) ++jc;
                while (jc > 0 && !maskj(jc - 1)) --jc;
            }
            c8 = jc;                 // keep = (j < c8)
        } else {
            double wst = (NYQ - flo) / dlt;
            double jr = wst * 96.0 + 1.0;
            int jl = (jr < 0.0) ? 0 : (jr > 96.0 ? 96 : (int)floor(jr));
            while (jl < 96 && !maskj(jl)) ++jl;
            while (jl > 0 && maskj(jl - 1)) --jl;
            c8 = -1 - jl;            // keep = (j >= -1-c8)
        }
    }

    int idx = frame * HH + lane;
    TabP[idx] = make_float4(0.0f, (float)(flo / 24000.0),
                            (float)(dlt / 24000.0), (float)a);
    // frame phase increment, revolutions: sum_j (flo + (j/96)*dlt)/24000
    OwnR[idx] = (96.0 * flo + 47.5 * dlt) / 24000.0;
    Cut[idx] = (signed char)c8;
}

// ---------------- Kernel B: frame-boundary phase prefix (f64) ----------------
// One wave per (b,h) chain; lanes = frames; 12 scan rounds of 750 frames.
// Writes exclusive prefix mod 1 into TabP[].x (f32 revolutions).
__global__ void k_phase(const double* __restrict__ OwnR,
                        float* __restrict__ TabPf) {
    int lane  = threadIdx.x & 63;
    int chain = blockIdx.x * 4 + (threadIdx.x >> 6);
    if (chain >= NCHAIN) return;
    int b = chain >> 6;
    int h = chain & 63;
    double carry = 0.0;
    for (int g = 0; g < (TT + 63) / 64; ++g) {
        int i = g * 64 + lane;
        double own = 0.0;
        if (i < TT) own = OwnR[(b * TT + i) * HH + h];
        double incl = own;
        for (int off = 1; off < 64; off <<= 1) {
            double o = __shfl_up(incl, off);
            if (lane >= off) incl += o;
        }
        if (i < TT) {
            double P = carry + (incl - own);        // exclusive prefix
            double p0 = P - rint(P);                // in [-0.5, 0.5]
            TabPf[((b * TT + i) * HH + h) * 4] = (float)p0;
        }
        carry += __shfl(incl, 63);
    }
}

// ---------------- Kernel C: synthesis (all f32) ----------------
// One thread per (b,s); 64-harmonic register loop; v_cos_f32 in revolutions.
__global__ void k_synth(const float4* __restrict__ TabP,
                        const signed char* __restrict__ Cut,
                        float* __restrict__ out) {
    int g = blockIdx.x * blockDim.x + threadIdx.x;
    if (g >= BB * NS) return;
    int b = g / NS;
    int s = g - b * NS;
    int i0 = s / UP;
    int j  = s - i0 * UP;
    int i1 = min(i0 + 1, TT - 1);
    int bt0 = (b * TT + i0) * HH;
    int bt1 = (b * TT + i1) * HH;

    float jp1 = (float)(j + 1);
    float V   = (float)(j * (j + 1)) * (1.0f / 192.0f);   // exact prefix of j/96
    float w32 = (float)j * (1.0f / 96.0f);

    const float* TF = (const float*)TabP;
    float acc = 0.0f;
    #pragma unroll 8
    for (int h = 0; h < HH; ++h) {
        float4 T = TabP[bt0 + h];                 // {p0, frev, drev, a0}
        float a1 = TF[(bt1 + h) * 4 + 3];         // next frame's a0
        int   c  = (int)Cut[bt0 + h];
        float ph = fmaf(jp1, T.y, T.x);
        ph = fmaf(V, T.z, ph);
        float fr = fract_f32(ph);                 // [0,1)
        float co = cos_rev(fr);                   // cos(2*pi*fr)
        float a  = fmaf(w32, a1 - T.w, T.w);
        bool keep = (c >= 0) ? (j < c) : (j >= -1 - c);
        float am = keep ? a : 0.0f;
        acc = fmaf(co, am, acc);
    }
    out[g] = acc;
}

extern "C" void kernel_launch(void* const* d_in, const int* in_sizes, int n_in,
                              void* d_out, int out_size, void* d_ws, size_t ws_size,
                              hipStream_t stream) {
    const float* amp_in = (const float*)d_in[0];   // (8,750,1)
    const float* hd_in  = (const float*)d_in[1];   // (8,750,64)
    const float* inh_in = (const float*)d_in[2];   // (8,750,1)
    const float* f0_in  = (const float*)d_in[3];   // (8,750,1)
    float* out = (float*)d_out;                    // (8,72000)

    char* ws = (char*)d_ws;
    float4*      TabP = (float4*)(ws);
    double*      OwnR = (double*)(ws + OFF_OWNR);
    signed char* Cut  = (signed char*)(ws + OFF_CUT);

    k_controls<<<(BB * TT) / 4, 256, 0, stream>>>(amp_in, hd_in, inh_in, f0_in,
                                                  TabP, OwnR, Cut);
    k_phase<<<NCHAIN / 4, 256, 0, stream>>>(OwnR, (float*)TabP);
    k_synth<<<(BB * NS) / 256, 256, 0, stream>>>(TabP, Cut, out);
}

// Round 5
// 93.096 us; speedup vs baseline: 1.8776x; 1.2064x over previous
//
#include <hip/hip_runtime.h>
#include <math.h>

#define TT 750
#define HH 64
#define BB 8
#define UP 96
#define NS (TT*UP)          // 72000 samples per batch
#define NCHAIN (BB*HH)      // 512
#define NYQ 12000.0
#define LN10f 2.30258509299404568402f

// ws layout:
//   TabQ : float4[6000*64]  {p0rev, frev, drev, cutbits}  6,144,000 B @ 0
//   Ha   : float[6000*64]   normalized amplitude          1,536,000 B @ 6,144,000
#define OFF_HA 6144000

__device__ inline float fract_f32(float x) {
#if __has_builtin(__builtin_amdgcn_fractf)
    return __builtin_amdgcn_fractf(x);
#else
    return x - floorf(x);
#endif
}

__device__ inline float cos_rev(float fr) {   // cos(2*pi*fr), fr in [0,1)
#if __has_builtin(__builtin_amdgcn_cosf)
    return __builtin_amdgcn_cosf(fr);
#else
    return __cosf(fr * 6.28318530717958647692f);
#endif
}

// ---------------- Kernel A: per-frame amplitudes (f32 fast path) ----------------
// One wave per (b,t) frame; lane = harmonic h. Sigmoid^ln10 in f32 (rel err
// ~1e-6, bounded effect); Nyquist gate for the normalization stays f64 so the
// discrete mask matches the f64 reference exactly.
__global__ void k_amps(const float* __restrict__ amp_in,
                       const float* __restrict__ hd_in,
                       const float* __restrict__ inh_in,
                       const float* __restrict__ f0_in,
                       float* __restrict__ Ha) {
    int wid  = threadIdx.x >> 6;
    int lane = threadIdx.x & 63;
    int frame = blockIdx.x * 4 + wid;          // grid is exact: 1500*4 = 6000

    float f0f = f0_in[frame];
    double bc = (double)inh_in[frame]; bc = bc > 0.0 ? bc : 0.0;
    double k  = (double)(lane + 1);
    double inh = ((double)f0f * k) * sqrt(1.0 + bc * k * k);

    float ax  = amp_in[frame];
    float sa  = 1.0f / (1.0f + __expf(-ax));
    float amp = 2.0f * __expf(LN10f * __logf(sa)) + 1e-7f;
    if (!(f0f > 20.0f)) amp = 0.0f;

    float hx = hd_in[frame * HH + lane];
    float sh = 1.0f / (1.0f + __expf(-hx));
    float hd = 2.0f * __expf(LN10f * __logf(sh)) + 1e-7f;
    if (!(inh < NYQ)) hd = 0.0f;               // frame-level nyquist cut (f64 compare)

    float ssum = hd;
    for (int off = 32; off; off >>= 1) ssum += __shfl_xor(ssum, off);
    // ssum >= 64e-7 > 0, no safe_divide branch needed
    Ha[frame * HH + lane] = amp * (hd / ssum);
}

// ---------------- Nyquist cut range (exact f64, contraction off) ----------------
__device__ void cut_range(int t, double flo, double fhi, int* plo, int* phi) {
#pragma clang fp contract(off)
    double dlt = fhi - flo;
    auto maskj = [&](int j) -> bool {
        double w = (double)(t * UP + j) / 96.0 - (double)t;
        double fr = flo * (1.0 - w) + fhi * w;
        return fr < NYQ;
    };
    if (dlt >= 0.0) {
        int jc;
        if (dlt == 0.0) jc = maskj(0) ? 96 : 0;
        else {
            double jr = (NYQ - flo) / dlt * 96.0;
            jc = (jr < 0.0) ? 0 : (jr > 96.0 ? 96 : (int)floor(jr));
            while (jc < 96 && maskj(jc)) ++jc;
            while (jc > 0 && !maskj(jc - 1)) --jc;
        }
        *plo = 0; *phi = jc;                   // keep = j < jc
    } else {
        double jr = (NYQ - flo) / dlt * 96.0 + 1.0;
        int jl = (jr < 0.0) ? 0 : (jr > 96.0 ? 96 : (int)floor(jr));
        while (jl < 96 && !maskj(jl)) ++jl;
        while (jl > 0 && maskj(jl - 1)) --jl;
        *plo = jl; *phi = 96;                  // keep = j >= jl
    }
}

// ---------------- Kernel B: per-chain frequencies + phase scan (f64) ----------------
// One 256-thread block per (b,h) chain. Frequencies into LDS once, f64 block
// scan for the frame-boundary phase prefix, Nyquist cut in the same pass.
__global__ __launch_bounds__(256) void k_chain(const float* __restrict__ inh_in,
                                               const float* __restrict__ f0_in,
                                               float4* __restrict__ TabQ) {
    __shared__ double Fl[TT + 1];
    __shared__ double Wsum[4];
    int b   = blockIdx.x >> 6;
    int h   = blockIdx.x & 63;
    int tid = threadIdx.x;
    double k = (double)(h + 1);

    for (int t = tid; t < TT; t += 256) {      // coalesced, L2-resident inputs
        double f0 = (double)f0_in[b * TT + t];
        double bc = (double)inh_in[b * TT + t]; bc = bc > 0.0 ? bc : 0.0;
        double stretch = sqrt(1.0 + bc * k * k);
        double inh = (f0 * k) * stretch;
        double den = fmax(f0, 1e-4) * k;       // > 0 always
        double shift = inh / den - 1.0;
        Fl[t] = (f0 * k) * (1.0 + shift);      // harmonic_frequencies
    }
    __syncthreads();
    if (tid == 0) Fl[TT] = Fl[TT - 1];
    __syncthreads();

    // per-frame phase increment (revolutions), threads 0..249 own 3 frames each
    int t0 = tid * 3;
    double own[3] = {0.0, 0.0, 0.0};
    double loc = 0.0;
    if (t0 < TT) {
        #pragma unroll
        for (int q = 0; q < 3; ++q) {
            int t = t0 + q;
            own[q] = (96.0 * Fl[t] + 47.5 * (Fl[t + 1] - Fl[t])) / 24000.0;
        }
        loc = own[0] + own[1] + own[2];
    }
    int lane = tid & 63, w = tid >> 6;
    double incl = loc;
    for (int off = 1; off < 64; off <<= 1) {
        double o = __shfl_up(incl, off);
        if (lane >= off) incl += o;
    }
    if (lane == 63) Wsum[w] = incl;
    __syncthreads();
    double carry = 0.0;
    for (int ww = 0; ww < w; ++ww) carry += Wsum[ww];
    double P = carry + (incl - loc);           // exclusive prefix at t0

    if (t0 < TT) {
        #pragma unroll
        for (int q = 0; q < 3; ++q) {
            int t = t0 + q;
            double flo = Fl[t], fhi = Fl[t + 1];
            int lo, hi;
            cut_range(t, flo, fhi, &lo, &hi);
            double pr = P - rint(P);           // [-0.5, 0.5]
            TabQ[(b * TT + t) * HH + h] = make_float4(
                (float)pr,
                (float)(flo / 24000.0),
                (float)((fhi - flo) / 24000.0),
                __int_as_float(lo | (hi << 8)));
            P += own[q];
        }
    }
}

// ---------------- Kernel C: synthesis (f32, 4 samples/thread) ----------------
__global__ __launch_bounds__(256) void k_synth(const float4* __restrict__ TabQ,
                                               const float*  __restrict__ Ha,
                                               float* __restrict__ out) {
    int g = blockIdx.x * 256 + threadIdx.x;
    if (g >= BB * NS / 4) return;
    int b  = g / (NS / 4);
    int r  = g - b * (NS / 4);
    int s0 = r * 4;                            // 4-aligned, never straddles a frame
    int i0 = s0 / UP;
    int j0 = s0 - i0 * UP;
    int i1 = min(i0 + 1, TT - 1);
    int bt0 = (b * TT + i0) * HH;
    int bt1 = (b * TT + i1) * HH;

    float jp1[4], Vv[4], wv[4];
    #pragma unroll
    for (int q = 0; q < 4; ++q) {
        int j = j0 + q;
        jp1[q] = (float)(j + 1);
        Vv[q]  = (float)(j * (j + 1)) * (1.0f / 192.0f);  // exact prefix of j/96
        wv[q]  = (float)j * (1.0f / 96.0f);
    }

    float acc[4] = {0.f, 0.f, 0.f, 0.f};
    #pragma unroll 4
    for (int h = 0; h < HH; ++h) {
        float4 T = TabQ[bt0 + h];              // {p0, frev, drev, cutbits}
        float a0 = Ha[bt0 + h];
        float a1 = Ha[bt1 + h];
        int cc = __float_as_int(T.w);
        int lo = cc & 0xff, hi = cc >> 8;
        float da = a1 - a0;
        #pragma unroll
        for (int q = 0; q < 4; ++q) {
            int j = j0 + q;
            float ph = fmaf(jp1[q], T.y, T.x);
            ph = fmaf(Vv[q], T.z, ph);
            float co = cos_rev(fract_f32(ph));
            float a  = fmaf(wv[q], da, a0);
            bool keep = (j >= lo) && (j < hi);
            acc[q] = fmaf(co, keep ? a : 0.0f, acc[q]);
        }
    }
    float4 o = make_float4(acc[0], acc[1], acc[2], acc[3]);
    *(float4*)(out + b * NS + s0) = o;         // 16B-aligned coalesced store
}

extern "C" void kernel_launch(void* const* d_in, const int* in_sizes, int n_in,
                              void* d_out, int out_size, void* d_ws, size_t ws_size,
                              hipStream_t stream) {
    const float* amp_in = (const float*)d_in[0];   // (8,750,1)
    const float* hd_in  = (const float*)d_in[1];   // (8,750,64)
    const float* inh_in = (const float*)d_in[2];   // (8,750,1)
    const float* f0_in  = (const float*)d_in[3];   // (8,750,1)
    float* out = (float*)d_out;                    // (8,72000)

    char* ws = (char*)d_ws;
    float4* TabQ = (float4*)(ws);
    float*  Ha   = (float*)(ws + OFF_HA);

    k_amps <<<(BB * TT) / 4, 256, 0, stream>>>(amp_in, hd_in, inh_in, f0_in, Ha);
    k_chain<<<NCHAIN,       256, 0, stream>>>(inh_in, f0_in, TabQ);
    k_synth<<<(BB * NS / 4 + 255) / 256, 256, 0, stream>>>(TabQ, Ha, out);
}